// Round 1
// baseline (120.062 us; speedup 1.0000x reference)
//
#include <hip/hip_runtime.h>
#include <math.h>

// Problem constants
#define Bb 16
#define Cc 256
#define Tt 1024

#define OFF_X   4194304   // recon size = 16*256*1024
#define OFF_LAT 8388608
#define OFF_ACT 8392704

// float32 roundings of the reference's double-precision constants
#define ALPHA_F 0.8187307530779818f     // exp(-1/5)
#define BETA_F  0.18126924692201815f    // 1 - exp(-1/5)
#define A16_F   0.04076220397836621f    // exp(-16/5) = alpha^16
#define THR_F   0.01f

// ---------------------------------------------------------------------------
// K1: precompute per-channel effective 9-tap kernel + bias (blocks 256),
//     and H[j][t][c] = og[j,c] * sum_d fw[j,c,d]*kp[c,d,t]  (blocks 0..255)
// ---------------------------------------------------------------------------
__global__ __launch_bounds__(256) void k_prep(
    const float* __restrict__ w3, const float* __restrict__ b3,
    const float* __restrict__ w5, const float* __restrict__ b5,
    const float* __restrict__ w9, const float* __restrict__ b9,
    const float* __restrict__ rw, const float* __restrict__ rb,
    const float* __restrict__ og, const float* __restrict__ fw,
    float* __restrict__ effb,   // [256][10]  (9 taps + bias)
    float* __restrict__ H)      // [256][9][256]  (j, t, c)
{
    const int c = threadIdx.x;
    const int j = blockIdx.x;
    if (j < 256) {
        float h[9];
        #pragma unroll
        for (int t = 0; t < 9; ++t) h[t] = 0.f;
        const float g = og[j * 256 + c];
        const float* fwp = fw + (j * 256 + c) * 18;
        const float* w3p = w3 + c * 18;
        const float* w5p = w5 + c * 30;
        const float* w9p = w9 + c * 54;
        #pragma unroll
        for (int oi = 0; oi < 6; ++oi) {
            const float f3 = fwp[oi], f5 = fwp[6 + oi], f9 = fwp[12 + oi];
            #pragma unroll
            for (int t = 0; t < 3; ++t) h[t] = fmaf(f3, w3p[oi * 3 + t], h[t]);
            #pragma unroll
            for (int t = 0; t < 5; ++t) h[t] = fmaf(f5, w5p[oi * 5 + t], h[t]);
            #pragma unroll
            for (int t = 0; t < 9; ++t) h[t] = fmaf(f9, w9p[oi * 9 + t], h[t]);
        }
        #pragma unroll
        for (int t = 0; t < 9; ++t) H[(j * 9 + t) * 256 + c] = g * h[t];
    } else {
        // effective centered kernel: drive[t] = beff + sum_r e[r] * x[t-4+r]
        float e[9];
        #pragma unroll
        for (int r = 0; r < 9; ++r) e[r] = 0.f;
        const float* rwp = rw + c * 18;
        const float* w3p = w3 + c * 18;
        const float* w5p = w5 + c * 30;
        const float* w9p = w9 + c * 54;
        float be = rb[c];
        #pragma unroll
        for (int oi = 0; oi < 6; ++oi) {
            const float r3 = rwp[oi], r5 = rwp[6 + oi], r9 = rwp[12 + oi];
            #pragma unroll
            for (int i = 0; i < 3; ++i) e[3 + i] = fmaf(r3, w3p[oi * 3 + i], e[3 + i]);
            #pragma unroll
            for (int i = 0; i < 5; ++i) e[2 + i] = fmaf(r5, w5p[oi * 5 + i], e[2 + i]);
            #pragma unroll
            for (int i = 0; i < 9; ++i) e[i]     = fmaf(r9, w9p[oi * 9 + i], e[i]);
            be = fmaf(r3, b3[c * 6 + oi], be);
            be = fmaf(r5, b5[c * 6 + oi], be);
            be = fmaf(r9, b9[c * 6 + oi], be);
        }
        #pragma unroll
        for (int r = 0; r < 9; ++r) effb[c * 10 + r] = e[r];
        effb[c * 10 + 9] = be;
    }
}

// ---------------------------------------------------------------------------
// K2: one 64-lane wave per (b,c) row. Fused conv-drive + parallel LIF scan.
//     Also writes the x-copy output (row is L1-hot) and lat/act.
// ---------------------------------------------------------------------------
__global__ __launch_bounds__(256) void k_lif(
    const float* __restrict__ x, const float* __restrict__ effb,
    const float* __restrict__ ls, float* __restrict__ out)
{
    const int lane = threadIdx.x & 63;
    const int wid  = threadIdx.x >> 6;
    const int row  = blockIdx.x * 4 + wid;       // 0..4095 = b*256 + c
    const int c    = row & 255;

    const float* xrow  = x + (size_t)row * Tt;
    const float4* xrow4 = reinterpret_cast<const float4*>(xrow);

    // Each lane owns t in [s, s+16); load halo'd window [s-4, s+20) as 6 float4s
    const int s = lane * 16;
    float xr[24];
    #pragma unroll
    for (int q = 0; q < 6; ++q) {
        const int t0 = s - 4 + 4 * q;
        float4 v = make_float4(0.f, 0.f, 0.f, 0.f);
        if (t0 >= 0 && t0 < Tt) v = xrow4[t0 >> 2];
        xr[q * 4 + 0] = v.x; xr[q * 4 + 1] = v.y;
        xr[q * 4 + 2] = v.z; xr[q * 4 + 3] = v.w;
    }

    float e[9];
    const float* ep = effb + c * 10;
    #pragma unroll
    for (int r = 0; r < 9; ++r) e[r] = ep[r];
    const float be = ep[9];

    // drive for own 16 timesteps
    float d[16];
    #pragma unroll
    for (int i = 0; i < 16; ++i) {
        float acc = be;
        #pragma unroll
        for (int r = 0; r < 9; ++r) acc = fmaf(e[r], xr[i + r], acc);
        d[i] = acc;
    }

    // local linear recurrence from V=0:  B_l
    float Bl = 0.f;
    #pragma unroll
    for (int i = 0; i < 16; ++i) Bl = fmaf(ALPHA_F, Bl, BETA_F * d[i]);

    // Hillis-Steele inclusive scan of (A,B) pairs across 64 lanes
    float Av = A16_F, Bv = Bl;
    #pragma unroll
    for (int o = 1; o < 64; o <<= 1) {
        const float Ap = __shfl_up(Av, (unsigned)o);
        const float Bp = __shfl_up(Bv, (unsigned)o);
        if (lane >= o) { Bv = fmaf(Av, Bp, Bv); Av = Av * Ap; }
    }
    float Vin = __shfl_up(Bv, 1u);
    if (lane == 0) Vin = 0.f;

    // replay to find first local crossing
    int local = -1;
    float V = Vin;
    #pragma unroll
    for (int i = 0; i < 16; ++i) {
        V = fmaf(ALPHA_F, V, BETA_F * d[i]);
        if (local < 0 && V >= THR_F) local = i;
    }
    const unsigned long long m = __ballot(local >= 0);
    float latf = 1024.f;
    if (m) {
        const int fl = __ffsll((unsigned long long)m) - 1;
        const int li = __shfl(local, fl);
        latf = (float)(fl * 16 + li);
    }
    const float scale = fmaxf(ls[0], 0.001f);
    const float act = expf(-latf / scale);

    // x passthrough output (coalesced; reads are L1-hot)
    float4* ox4 = reinterpret_cast<float4*>(out + OFF_X) + (size_t)row * 256;
    #pragma unroll
    for (int q = 0; q < 4; ++q) ox4[lane + 64 * q] = xrow4[lane + 64 * q];

    if (lane == 0) {
        out[OFF_LAT + row] = latf;
        out[OFF_ACT + row] = act;
    }
}

// ---------------------------------------------------------------------------
// K3: recon[b,j,t] = sum_c act[b,c]*H[j,t,c] for t<9, zero for t>=9.
//     One block per (b,j); writes the full 1024-float row coalesced.
// ---------------------------------------------------------------------------
__global__ __launch_bounds__(256) void k_recon(
    const float* __restrict__ H, const float* __restrict__ actp,
    float* __restrict__ out)
{
    const int tid = threadIdx.x;
    const int bid = blockIdx.x;          // 0..4095
    const int b = bid >> 8, j = bid & 255;

    const float a = actp[b * 256 + tid];
    float p[9];
    #pragma unroll
    for (int t = 0; t < 9; ++t) p[t] = a * H[(j * 9 + t) * 256 + tid];

    #pragma unroll
    for (int t = 0; t < 9; ++t) {
        #pragma unroll
        for (int o = 32; o > 0; o >>= 1) p[t] += __shfl_xor(p[t], o);
    }

    __shared__ float red[4][12];
    __shared__ float rs[12];
    const int lane = tid & 63, wid = tid >> 6;
    if (lane == 0) {
        #pragma unroll
        for (int t = 0; t < 9; ++t) red[wid][t] = p[t];
    }
    __syncthreads();
    if (tid < 9) rs[tid] = red[0][tid] + red[1][tid] + red[2][tid] + red[3][tid];
    __syncthreads();

    float4 v = make_float4(0.f, 0.f, 0.f, 0.f);
    if (tid == 0)      v = make_float4(rs[0], rs[1], rs[2], rs[3]);
    else if (tid == 1) v = make_float4(rs[4], rs[5], rs[6], rs[7]);
    else if (tid == 2) v = make_float4(rs[8], 0.f, 0.f, 0.f);
    reinterpret_cast<float4*>(out)[(size_t)bid * 256 + tid] = v;
}

// ---------------------------------------------------------------------------
extern "C" void kernel_launch(void* const* d_in, const int* in_sizes, int n_in,
                              void* d_out, int out_size, void* d_ws, size_t ws_size,
                              hipStream_t stream) {
    const float* x  = (const float*)d_in[0];
    const float* w3 = (const float*)d_in[1];
    const float* b3 = (const float*)d_in[2];
    const float* w5 = (const float*)d_in[3];
    const float* b5 = (const float*)d_in[4];
    const float* w9 = (const float*)d_in[5];
    const float* b9 = (const float*)d_in[6];
    const float* rw = (const float*)d_in[7];
    const float* rb = (const float*)d_in[8];
    const float* ls = (const float*)d_in[9];
    const float* og = (const float*)d_in[10];
    const float* fw = (const float*)d_in[11];
    float* out = (float*)d_out;

    float* effb = (float*)d_ws;          // 2560 floats
    float* H    = (float*)d_ws + 2560;   // 589824 floats (2.3 MB)

    k_prep<<<dim3(257), dim3(256), 0, stream>>>(w3, b3, w5, b5, w9, b9,
                                                rw, rb, og, fw, effb, H);
    k_lif<<<dim3(1024), dim3(256), 0, stream>>>(x, effb, ls, out);
    k_recon<<<dim3(4096), dim3(256), 0, stream>>>(H, out + OFF_ACT, out);
}

// Round 2
// 113.207 us; speedup vs baseline: 1.0606x; 1.0606x over previous
//
#include <hip/hip_runtime.h>
#include <math.h>

// Problem constants
#define Bb 16
#define Cc 256
#define Tt 1024

#define OFF_X   4194304   // recon size = 16*256*1024
#define OFF_LAT 8388608
#define OFF_ACT 8392704

// float32 roundings of the reference's double-precision constants
#define ALPHA_F 0.8187307530779818f     // exp(-1/5)
#define BETA_F  0.18126924692201815f    // 1 - exp(-1/5)
#define A16_F   0.04076220397836621f    // exp(-16/5) = alpha^16
#define THR_F   0.01f

// ---------------------------------------------------------------------------
// K1 "main": blocks [0,1024)  : one 64-lane wave per (b,c) row — fused
//                               conv-drive + parallel LIF scan + x-copy +
//                               lat/act. Effective 9-tap kernel computed
//                               in-wave (lane-distributed, butterfly-summed).
//            blocks [1024,1280): H[j][t][c] = og[j,c]*sum_d fw[j,c,d]*kp[c,d,t]
//            (the two halves are independent)
// ---------------------------------------------------------------------------
__global__ __launch_bounds__(256) void k_main(
    const float* __restrict__ x,
    const float* __restrict__ w3, const float* __restrict__ b3,
    const float* __restrict__ w5, const float* __restrict__ b5,
    const float* __restrict__ w9, const float* __restrict__ b9,
    const float* __restrict__ rw, const float* __restrict__ rb,
    const float* __restrict__ ls, const float* __restrict__ og,
    const float* __restrict__ fw,
    float* __restrict__ H, float* __restrict__ out)
{
    const int bid = blockIdx.x;
    const int tid = threadIdx.x;

    if (bid >= 1024) {
        // ---- H precompute: one block per output channel j, thread = c ----
        const int j = bid - 1024;
        const int c = tid;
        float h[9];
        #pragma unroll
        for (int t = 0; t < 9; ++t) h[t] = 0.f;
        const float g = og[j * 256 + c];
        const float* fwp = fw + (j * 256 + c) * 18;
        const float* w3p = w3 + c * 18;
        const float* w5p = w5 + c * 30;
        const float* w9p = w9 + c * 54;
        #pragma unroll
        for (int oi = 0; oi < 6; ++oi) {
            const float f3 = fwp[oi], f5 = fwp[6 + oi], f9 = fwp[12 + oi];
            #pragma unroll
            for (int t = 0; t < 3; ++t) h[t] = fmaf(f3, w3p[oi * 3 + t], h[t]);
            #pragma unroll
            for (int t = 0; t < 5; ++t) h[t] = fmaf(f5, w5p[oi * 5 + t], h[t]);
            #pragma unroll
            for (int t = 0; t < 9; ++t) h[t] = fmaf(f9, w9p[oi * 9 + t], h[t]);
        }
        #pragma unroll
        for (int t = 0; t < 9; ++t) H[(j * 9 + t) * 256 + c] = g * h[t];
        return;
    }

    // ---- LIF: one wave per (b,c) row ----
    const int lane = tid & 63;
    const int wid  = tid >> 6;
    const int row  = bid * 4 + wid;       // 0..4095 = b*256 + c
    const int c    = row & 255;

    // effective centered 9-tap kernel + bias, lane-distributed over d=0..17
    float el[9];
    #pragma unroll
    for (int r = 0; r < 9; ++r) el[r] = 0.f;
    float bl = 0.f;
    if (lane < 18) {
        const float r = rw[c * 18 + lane];
        if (lane < 6) {
            const int oi = lane;
            #pragma unroll
            for (int i = 0; i < 3; ++i) el[3 + i] = r * w3[c * 18 + oi * 3 + i];
            bl = r * b3[c * 6 + oi];
        } else if (lane < 12) {
            const int oi = lane - 6;
            #pragma unroll
            for (int i = 0; i < 5; ++i) el[2 + i] = r * w5[c * 30 + oi * 5 + i];
            bl = r * b5[c * 6 + oi];
        } else {
            const int oi = lane - 12;
            #pragma unroll
            for (int i = 0; i < 9; ++i) el[i] = r * w9[c * 54 + oi * 9 + i];
            bl = r * b9[c * 6 + oi];
        }
    }
    #pragma unroll
    for (int o = 1; o < 64; o <<= 1) {
        #pragma unroll
        for (int r = 0; r < 9; ++r) el[r] += __shfl_xor(el[r], o);
        bl += __shfl_xor(bl, o);
    }
    float e[9];
    #pragma unroll
    for (int r = 0; r < 9; ++r) e[r] = el[r];
    const float be = bl + rb[c];

    const float* xrow  = x + (size_t)row * Tt;
    const float4* xrow4 = reinterpret_cast<const float4*>(xrow);

    // Each lane owns t in [s, s+16); load halo'd window [s-4, s+20) as 6 float4s
    const int s = lane * 16;
    float xr[24];
    #pragma unroll
    for (int q = 0; q < 6; ++q) {
        const int t0 = s - 4 + 4 * q;
        float4 v = make_float4(0.f, 0.f, 0.f, 0.f);
        if (t0 >= 0 && t0 < Tt) v = xrow4[t0 >> 2];
        xr[q * 4 + 0] = v.x; xr[q * 4 + 1] = v.y;
        xr[q * 4 + 2] = v.z; xr[q * 4 + 3] = v.w;
    }

    // drive for own 16 timesteps
    float d[16];
    #pragma unroll
    for (int i = 0; i < 16; ++i) {
        float acc = be;
        #pragma unroll
        for (int r = 0; r < 9; ++r) acc = fmaf(e[r], xr[i + r], acc);
        d[i] = acc;
    }

    // local linear recurrence from V=0:  B_l
    float Bl = 0.f;
    #pragma unroll
    for (int i = 0; i < 16; ++i) Bl = fmaf(ALPHA_F, Bl, BETA_F * d[i]);

    // Hillis-Steele inclusive scan of (A,B) pairs across 64 lanes
    float Av = A16_F, Bv = Bl;
    #pragma unroll
    for (int o = 1; o < 64; o <<= 1) {
        const float Ap = __shfl_up(Av, (unsigned)o);
        const float Bp = __shfl_up(Bv, (unsigned)o);
        if (lane >= o) { Bv = fmaf(Av, Bp, Bv); Av = Av * Ap; }
    }
    float Vin = __shfl_up(Bv, 1u);
    if (lane == 0) Vin = 0.f;

    // replay to find first local crossing
    int local = -1;
    float V = Vin;
    #pragma unroll
    for (int i = 0; i < 16; ++i) {
        V = fmaf(ALPHA_F, V, BETA_F * d[i]);
        if (local < 0 && V >= THR_F) local = i;
    }
    const unsigned long long m = __ballot(local >= 0);
    float latf = 1024.f;
    if (m) {
        const int fl = __ffsll((unsigned long long)m) - 1;
        const int li = __shfl(local, fl);
        latf = (float)(fl * 16 + li);
    }
    const float scale = fmaxf(ls[0], 0.001f);
    const float act = expf(-latf / scale);

    // x passthrough output (coalesced; reads are cache-hot)
    float4* ox4 = reinterpret_cast<float4*>(out + OFF_X) + (size_t)row * 256;
    #pragma unroll
    for (int q = 0; q < 4; ++q) ox4[lane + 64 * q] = xrow4[lane + 64 * q];

    if (lane == 0) {
        out[OFF_LAT + row] = latf;
        out[OFF_ACT + row] = act;
    }
}

// ---------------------------------------------------------------------------
// K2: recon[b,j,t] = sum_c act[b,c]*H[j,t,c] for t<9, zero for t>=9.
//     One block per (b,j); writes the full 1024-float row coalesced.
// ---------------------------------------------------------------------------
__global__ __launch_bounds__(256) void k_recon(
    const float* __restrict__ H, const float* __restrict__ actp,
    float* __restrict__ out)
{
    const int tid = threadIdx.x;
    const int bid = blockIdx.x;          // 0..4095
    const int b = bid >> 8, j = bid & 255;

    const float a = actp[b * 256 + tid];
    float p[9];
    #pragma unroll
    for (int t = 0; t < 9; ++t) p[t] = a * H[(j * 9 + t) * 256 + tid];

    #pragma unroll
    for (int t = 0; t < 9; ++t) {
        #pragma unroll
        for (int o = 32; o > 0; o >>= 1) p[t] += __shfl_xor(p[t], o);
    }

    __shared__ float red[4][12];
    __shared__ float rs[12];
    const int lane = tid & 63, wid = tid >> 6;
    if (lane == 0) {
        #pragma unroll
        for (int t = 0; t < 9; ++t) red[wid][t] = p[t];
    }
    __syncthreads();
    if (tid < 9) rs[tid] = red[0][tid] + red[1][tid] + red[2][tid] + red[3][tid];
    __syncthreads();

    float4 v = make_float4(0.f, 0.f, 0.f, 0.f);
    if (tid == 0)      v = make_float4(rs[0], rs[1], rs[2], rs[3]);
    else if (tid == 1) v = make_float4(rs[4], rs[5], rs[6], rs[7]);
    else if (tid == 2) v = make_float4(rs[8], 0.f, 0.f, 0.f);
    reinterpret_cast<float4*>(out)[(size_t)bid * 256 + tid] = v;
}

// ---------------------------------------------------------------------------
extern "C" void kernel_launch(void* const* d_in, const int* in_sizes, int n_in,
                              void* d_out, int out_size, void* d_ws, size_t ws_size,
                              hipStream_t stream) {
    const float* x  = (const float*)d_in[0];
    const float* w3 = (const float*)d_in[1];
    const float* b3 = (const float*)d_in[2];
    const float* w5 = (const float*)d_in[3];
    const float* b5 = (const float*)d_in[4];
    const float* w9 = (const float*)d_in[5];
    const float* b9 = (const float*)d_in[6];
    const float* rw = (const float*)d_in[7];
    const float* rb = (const float*)d_in[8];
    const float* ls = (const float*)d_in[9];
    const float* og = (const float*)d_in[10];
    const float* fw = (const float*)d_in[11];
    float* out = (float*)d_out;

    float* H = (float*)d_ws;   // 589824 floats (2.3 MB)

    k_main<<<dim3(1280), dim3(256), 0, stream>>>(x, w3, b3, w5, b5, w9, b9,
                                                 rw, rb, ls, og, fw, H, out);
    k_recon<<<dim3(4096), dim3(256), 0, stream>>>(H, out + OFF_ACT, out);
}